// Round 3
// baseline (407.621 us; speedup 1.0000x reference)
//
#include <hip/hip_runtime.h>
#include <hip/hip_bf16.h>
#include <math.h>

#define N_  512
#define D_  384
#define H_  12
#define DK_ 32
#define P_  128

#define PROJ_B 320    // proj blocks FIRST (overlap under pair phase)
#define PAIR_B 512    // persistent pair-GEMM blocks, 6 waves each

typedef short short8 __attribute__((ext_vector_type(8)));
typedef float f32x4  __attribute__((ext_vector_type(4)));

static __device__ __forceinline__ unsigned short f2bf(float f) {
    union { float f; unsigned int u; } v; v.f = f;
    unsigned int r = (v.u + 0x7FFFu + ((v.u >> 16) & 1u)) >> 16;  // RNE
    return (unsigned short)r;
}
static __device__ __forceinline__ float bf2f(unsigned short u) {
    union { unsigned int u; float f; } v; v.u = ((unsigned int)u) << 16;
    return v.f;
}
static __device__ __forceinline__ short2 pk2bf(float a, float b) {
    __hip_bfloat162 h = __float22bfloat162_rn(make_float2(a, b));
    return *(short2*)&h;
}
typedef union { short8 v; short2 h2[4]; } s8u;

// ---------------------------------------------------------------------------
// K1: blocks 0..319 = projections+affine (8 rows/block, scheduled first);
// blocks 320..831 = persistent pair-bias MFMA GEMM. Pair loads are FULLY
// COALESCED (lane-major 16B granules, 1KB/instr) -> XOR-swizzled LDS bounce
// -> MFMA fragments. 3-deep register pipeline, all loads unconditional.
// ---------------------------------------------------------------------------
__global__ __launch_bounds__(384, 3) void k_front(
    const float* __restrict__ x2d, const float* __restrict__ w_pb,
    float* __restrict__ pairlog,
    const float* __restrict__ x1d, const float* __restrict__ pose_t,
    const float* __restrict__ pose_r,
    const float* __restrict__ w_sq, const float* __restrict__ w_sk,
    const float* __restrict__ w_sv, const float* __restrict__ w_pq,
    const float* __restrict__ w_pk, const float* __restrict__ w_pv,
    float* __restrict__ qs, float* __restrict__ kst,
    float* __restrict__ qp, float* __restrict__ kpt,
    unsigned short* __restrict__ vcatT)
{
    __shared__ float smem[12288];   // 48KB: pair = 8KB/wave x 6; proj aliases

    const int t = threadIdx.x;

    if (blockIdx.x >= PROJ_B) {
        // ---------------- pair-bias logits (persistent MFMA) ----------------
        const int pb   = blockIdx.x - PROJ_B;   // 0..511
        const int wid  = t >> 6;                // 0..5
        const int lane = t & 63;
        const int quad = lane >> 4;
        const int col  = lane & 15;
        const int gw   = pb * 6 + wid;          // 0..3071 global wave id
        const float pair_w = 0.57735027f;

        float* wl = smem + wid * 2048;          // private 8KB tile buffer

        short8 bfr[4];
        #pragma unroll
        for (int kt = 0; kt < 4; ++kt) {
            #pragma unroll
            for (int jj = 0; jj < 8; ++jj) {
                int p = kt * 32 + quad * 8 + jj;
                bfr[kt][jj] = (col < 12) ? (short)f2bf(w_pb[p * 12 + col]) : (short)0;
            }
        }

        // coalesced load: lane-major granules, 1KB contiguous per instruction
        auto LDT = [&](float4* f, int T) {
            const float* tb = x2d + ((size_t)((T >> 5) * N_ + ((T & 31) << 4))) * P_;
            #pragma unroll
            for (int k = 0; k < 8; ++k)
                f[k] = *(const float4*)(tb + k * 256 + lane * 4);
        };
        // stage regs -> swizzled LDS, read MFMA fragments, compute, store
        auto CMP = [&](const float4* f, int T, bool dostore) {
            #pragma unroll
            for (int k = 0; k < 8; ++k) {
                int off  = k * 1024 + lane * 16;
                int soff = off ^ (((off >> 9) & 7) << 4);   // row-XOR swizzle
                *(float4*)((char*)wl + soff) = f[k];
            }
            f32x4 acc = {0.f, 0.f, 0.f, 0.f};
            #pragma unroll
            for (int kt = 0; kt < 4; ++kt) {
                int g0 = (col * 512 + kt * 128 + quad * 32) ^ ((col & 7) << 4);
                float4 x0 = *(const float4*)((const char*)wl + g0);
                float4 x1 = *(const float4*)((const char*)wl + (g0 ^ 16));
                s8u afr;
                afr.h2[0] = pk2bf(x0.x, x0.y);
                afr.h2[1] = pk2bf(x0.z, x0.w);
                afr.h2[2] = pk2bf(x1.x, x1.y);
                afr.h2[3] = pk2bf(x1.z, x1.w);
                acc = __builtin_amdgcn_mfma_f32_16x16x32_bf16(afr.v, bfr[kt], acc, 0, 0, 0);
            }
            if (dostore && col < 12) {
                const int i  = T >> 5;
                const int j0 = (T & 31) << 4;
                float4 st = make_float4(pair_w * acc[0], pair_w * acc[1],
                                        pair_w * acc[2], pair_w * acc[3]);
                *(float4*)(pairlog + ((size_t)(col * N_ + i)) * N_ + j0 + quad * 4) = st;
            }
        };

        // tiles gw + 3072*s; s=0..4 always < 16384; s=5 only if gw < 1024
        const bool has6 = (gw + 15360) < 16384;
        const int  T5   = has6 ? (gw + 15360) : gw;   // clamp: load anyway

        float4 fA[8], fB[8], fC[8];
        LDT(fA, gw);
        LDT(fB, gw + 3072);
        LDT(fC, gw + 6144);   CMP(fA, gw,          true);
        LDT(fA, gw + 9216);   CMP(fB, gw + 3072,   true);
        LDT(fB, gw + 12288);  CMP(fC, gw + 6144,   true);
        LDT(fC, T5);          CMP(fA, gw + 9216,   true);
        CMP(fB, gw + 12288, true);
        CMP(fC, T5, has6);
        return;
    }

    // ---------------- projections + affine (8 rows/block) ----------------
    float (*raw)[288] = reinterpret_cast<float(*)[288]>(smem);
    float (*Rsh)[9]   = reinterpret_cast<float(*)[9]>(smem + 2304);
    float (*Tsh)[3]   = reinterpret_cast<float(*)[3]>(smem + 2304 + 72);

    const int b   = blockIdx.x;
    const int seg = b >> 6;            // 0..4
    const int i0  = (b & 63) * 8;

    if (seg < 3) {
        const float* __restrict__ w = (seg == 0) ? w_sq : (seg == 1) ? w_sk : w_sv;
        float acc[8];
        #pragma unroll
        for (int r = 0; r < 8; ++r) acc[r] = 0.f;
        for (int d = 0; d < D_; d += 4) {
            float4 xr[8];
            #pragma unroll
            for (int r = 0; r < 8; ++r)
                xr[r] = *(const float4*)(x1d + (i0 + r) * D_ + d);
            #pragma unroll
            for (int e = 0; e < 4; ++e) {
                float wv = w[(d + e) * D_ + t];
                #pragma unroll
                for (int r = 0; r < 8; ++r)
                    acc[r] += ((const float*)&xr[r])[e] * wv;
            }
        }
        if (seg == 0) {
            #pragma unroll
            for (int r = 0; r < 8; ++r) qs[(i0 + r) * D_ + t] = acc[r];
        } else if (seg == 1) {
            *(float4*)(kst + t * N_ + i0)     = make_float4(acc[0], acc[1], acc[2], acc[3]);
            *(float4*)(kst + t * N_ + i0 + 4) = make_float4(acc[4], acc[5], acc[6], acc[7]);
        } else {
            int h = t >> 5, c = t & 31;
            s8u sv;
            #pragma unroll
            for (int r = 0; r < 4; ++r) sv.h2[r] = pk2bf(acc[2*r], acc[2*r+1]);
            *(short8*)(vcatT + ((size_t)h * 64 + c) * N_ + i0) = sv.v;
        }
    } else {
        if (t < 72) Rsh[t / 9][t % 9] = pose_r[(i0 + t / 9) * 9 + t % 9];
        else if (t < 96) {
            int r = (t - 72) / 3, c = (t - 72) % 3;
            Tsh[r][c] = pose_t[(i0 + r) * 3 + c];
        }

        if (t < 288) {
            const float* __restrict__ w;
            int col, ldw;
            if (seg == 3) {
                if (t < 144) { w = w_pq; col = t;       ldw = 144; }
                else         { w = w_pk; col = t - 144; ldw = 144; }
            } else         { w = w_pv; col = t;       ldw = 288; }
            float acc[8];
            #pragma unroll
            for (int r = 0; r < 8; ++r) acc[r] = 0.f;
            for (int d = 0; d < D_; d += 4) {
                float4 xr[8];
                #pragma unroll
                for (int r = 0; r < 8; ++r)
                    xr[r] = *(const float4*)(x1d + (i0 + r) * D_ + d);
                #pragma unroll
                for (int e = 0; e < 4; ++e) {
                    float wv = w[(d + e) * ldw + col];
                    #pragma unroll
                    for (int r = 0; r < 8; ++r)
                        acc[r] += ((const float*)&xr[r])[e] * wv;
                }
            }
            #pragma unroll
            for (int r = 0; r < 8; ++r) raw[r][t] = acc[r];
        }
        __syncthreads();

        if (t < 288) {
            const int x3   = t % 3;
            const int base = t - x3;
            if (seg == 3) {
                const int c = (t < 144) ? t : t - 144;
                if (t < 144) {
                    #pragma unroll
                    for (int r = 0; r < 8; ++r) {
                        float g = Rsh[r][0 + x3] * raw[r][base]
                                + Rsh[r][3 + x3] * raw[r][base + 1]
                                + Rsh[r][6 + x3] * raw[r][base + 2] + Tsh[r][x3];
                        qp[(i0 + r) * 144 + c] = g;
                    }
                } else {
                    float g[8];
                    #pragma unroll
                    for (int r = 0; r < 8; ++r)
                        g[r] = Rsh[r][0 + x3] * raw[r][base]
                             + Rsh[r][3 + x3] * raw[r][base + 1]
                             + Rsh[r][6 + x3] * raw[r][base + 2] + Tsh[r][x3];
                    *(float4*)(kpt + c * N_ + i0)     = make_float4(g[0], g[1], g[2], g[3]);
                    *(float4*)(kpt + c * N_ + i0 + 4) = make_float4(g[4], g[5], g[6], g[7]);
                }
            } else {
                int h = t / 24, pc = t % 24;
                float g[8];
                #pragma unroll
                for (int r = 0; r < 8; ++r)
                    g[r] = Rsh[r][0 + x3] * raw[r][base]
                         + Rsh[r][3 + x3] * raw[r][base + 1]
                         + Rsh[r][6 + x3] * raw[r][base + 2] + Tsh[r][x3];
                s8u sv;
                #pragma unroll
                for (int r = 0; r < 4; ++r) sv.h2[r] = pk2bf(g[2*r], g[2*r+1]);
                *(short8*)(vcatT + ((size_t)h * 64 + 32 + pc) * N_ + i0) = sv.v;
            }
        }
    }
}

// ---------------------------------------------------------------------------
// K2 (fused): scalar+point+bias logits + pair logits read + softmax,
// all in registers. Writes ONLY bf16 attn. Block = (h, 4 rows), 256 thr.
// ---------------------------------------------------------------------------
__global__ __launch_bounds__(256) void k_sp_soft(
    const float* __restrict__ qs, const float* __restrict__ kst,
    const float* __restrict__ qp, const float* __restrict__ kpt,
    const float* __restrict__ bias, const float* __restrict__ tpw,
    const float* __restrict__ pairlog,
    unsigned short* __restrict__ attn_bf)
{
    const int h  = blockIdx.x / 128;
    const int i0 = (blockIdx.x % 128) * 4;
    const int t  = threadIdx.x;
    const int lane = t & 63;
    const int wid  = t >> 6;
    __shared__ float qsh[4][32];
    __shared__ float qph[4][12];
    __shared__ float wredm[4][4];
    __shared__ float wreds[4][4];
    if (t < 128) { int il = t / 32, c = t % 32; qsh[il][c] = qs[(i0+il) * D_ + h*32 + c]; }
    else if (t < 176) { int r = t - 128; int il = r / 12, c = r % 12; qph[il][c] = qp[(i0+il)*144 + h*12 + c]; }
    const float pwh = 0.13608276f * log1pf(expf(tpw[h]));
    const float scalar_w = 0.10206207f;
    __syncthreads();

    float v[4][2];
    for (int jh = 0; jh < 2; ++jh) {
        int j = t + jh * 256;
        float kv[32];
        #pragma unroll
        for (int c = 0; c < 32; ++c) kv[c] = kst[(h*32 + c) * N_ + j];
        float kp[12];
        #pragma unroll
        for (int c = 0; c < 12; ++c) kp[c] = kpt[(h*12 + c) * N_ + j];

        #pragma unroll
        for (int il = 0; il < 4; ++il) {
            float s = 0.f;
            #pragma unroll
            for (int c = 0; c < 32; ++c) s += qsh[il][c] * kv[c];
            float dsum = 0.f;
            #pragma unroll
            for (int p = 0; p < 4; ++p) {
                float dx = qph[il][p*3+0] - kp[p*3+0];
                float dy = qph[il][p*3+1] - kp[p*3+1];
                float dz = qph[il][p*3+2] - kp[p*3+2];
                dsum += sqrtf(dx*dx + dy*dy + dz*dz);
            }
            v[il][jh] = scalar_w * s - 0.5f * pwh * dsum
                      + bias[(i0+il) * N_ + j]
                      + pairlog[((size_t)(h * N_ + (i0+il))) * N_ + j];
        }
    }

    // row max
    #pragma unroll
    for (int il = 0; il < 4; ++il) {
        float mt = fmaxf(v[il][0], v[il][1]);
        #pragma unroll
        for (int off = 1; off < 64; off <<= 1)
            mt = fmaxf(mt, __shfl_xor(mt, off));
        if (lane == 0) wredm[il][wid] = mt;
    }
    __syncthreads();
    float m[4];
    #pragma unroll
    for (int il = 0; il < 4; ++il)
        m[il] = fmaxf(fmaxf(wredm[il][0], wredm[il][1]),
                      fmaxf(wredm[il][2], wredm[il][3]));

    // exp + row sum
    #pragma unroll
    for (int il = 0; il < 4; ++il) {
        float e0 = __expf(v[il][0] - m[il]);
        float e1 = __expf(v[il][1] - m[il]);
        v[il][0] = e0; v[il][1] = e1;
        float st = e0 + e1;
        #pragma unroll
        for (int off = 1; off < 64; off <<= 1)
            st += __shfl_xor(st, off);
        if (lane == 0) wreds[il][wid] = st;
    }
    __syncthreads();
    #pragma unroll
    for (int il = 0; il < 4; ++il) {
        float inv = 1.0f / (wreds[il][0] + wreds[il][1] + wreds[il][2] + wreds[il][3]);
        size_t base = ((size_t)(h * N_ + i0 + il)) * N_;
        attn_bf[base + t]       = f2bf(v[il][0] * inv);
        attn_bf[base + t + 256] = f2bf(v[il][1] * inv);
    }
}

// ---------------------------------------------------------------------------
// K3 (merged): blocks 0..511 = tmp (attn_bf @ x2d per row i);
// blocks 512..895 = aggr (attn_bf @ vcatT via MFMA).
// ---------------------------------------------------------------------------
__global__ __launch_bounds__(256) void k_mid(
    const unsigned short* __restrict__ attn_bf,
    const float* __restrict__ x2d,
    const unsigned short* __restrict__ vcatT,
    float* __restrict__ tmp,
    float* __restrict__ feat, float* __restrict__ outpg)
{
    __shared__ float4 at[3][N_];
    __shared__ float red[4][1536];

    const int t = threadIdx.x;

    if (blockIdx.x < 512) {
        const int i = blockIdx.x;
        // stage bf16 attn -> fp32 LDS
        for (int idx = t; idx < 12 * N_; idx += 256) {
            int h = idx >> 9, j = idx & 511;
            float a = bf2f(attn_bf[((size_t)(h * N_ + i)) * N_ + j]);
            ((float*)&at[h >> 2][j])[h & 3] = a;
        }
        __syncthreads();

        const int p2 = (t & 63) * 2;
        const int jh = t >> 6;
        float acc[12][2];
        #pragma unroll
        for (int h = 0; h < 12; ++h) { acc[h][0] = 0.f; acc[h][1] = 0.f; }
        const float* xb = x2d + (size_t)i * N_ * P_;

        #pragma unroll 4
        for (int j = jh; j < N_; j += 4) {
            float2 x = *(const float2*)(xb + j * P_ + p2);
            float4 a0 = at[0][j], a1 = at[1][j], a2 = at[2][j];
            acc[0][0]  += a0.x*x.x; acc[0][1]  += a0.x*x.y;
            acc[1][0]  += a0.y*x.x; acc[1][1]  += a0.y*x.y;
            acc[2][0]  += a0.z*x.x; acc[2][1]  += a0.z*x.y;
            acc[3][0]  += a0.w*x.x; acc[3][1]  += a0.w*x.y;
            acc[4][0]  += a1.x*x.x; acc[4][1]  += a1.x*x.y;
            acc[5][0]  += a1.y*x.x; acc[5][1]  += a1.y*x.y;
            acc[6][0]  += a1.z*x.x; acc[6][1]  += a1.z*x.y;
            acc[7][0]  += a1.w*x.x; acc[7][1]  += a1.w*x.y;
            acc[8][0]  += a2.x*x.x; acc[8][1]  += a2.x*x.y;
            acc[9][0]  += a2.y*x.x; acc[9][1]  += a2.y*x.y;
            acc[10][0] += a2.z*x.x; acc[10][1] += a2.z*x.y;
            acc[11][0] += a2.w*x.x; acc[11][1] += a2.w*x.y;
        }
        #pragma unroll
        for (int h = 0; h < 12; ++h) {
            red[jh][h * 128 + p2]     = acc[h][0];
            red[jh][h * 128 + p2 + 1] = acc[h][1];
        }
        __syncthreads();
        for (int idx = t; idx < 1536; idx += 256)
            tmp[(size_t)i * 1536 + idx] = red[0][idx] + red[1][idx] + red[2][idx] + red[3][idx];
        return;
    }

    // ---------------- aggr (MFMA) ----------------
    const int bid  = blockIdx.x - 512;
    const int h    = bid >> 5;
    const int i0   = (bid & 31) << 4;
    const int wid  = t >> 6;
    const int lane = t & 63;
    const int quad = lane >> 4;
    const int col  = lane & 15;
    const int c    = wid * 16 + col;
    const bool cvalid = (c < 56);

    const unsigned short* arow = attn_bf + ((size_t)(h * N_ + i0 + col)) * N_;
    const unsigned short* brow = vcatT + ((size_t)h * 64 + c) * N_;

    f32x4 acc = {0.f, 0.f, 0.f, 0.f};
    #pragma unroll
    for (int kt = 0; kt < 16; ++kt) {
        const int k0 = kt * 32 + quad * 8;
        short8 a = *(const short8*)(arow + k0);
        short8 b;
        if (cvalid) b = *(const short8*)(brow + k0);
        else { b[0]=0;b[1]=0;b[2]=0;b[3]=0;b[4]=0;b[5]=0;b[6]=0;b[7]=0; }
        acc = __builtin_amdgcn_mfma_f32_16x16x32_bf16(a, b, acc, 0, 0, 0);
    }
    #pragma unroll
    for (int r = 0; r < 4; ++r) {
        int i = i0 + quad * 4 + r;
        if (c < 32)       feat[(size_t)i * 1152 + h * 32 + c] = acc[r];
        else if (c < 56)  outpg[((size_t)i * 12 + h) * 24 + (c - 32)] = acc[r];
    }
}

__global__ __launch_bounds__(384) void k_feat(
    const float* __restrict__ tmp, const float* __restrict__ outpg,
    const float* __restrict__ pose_t, const float* __restrict__ pose_r,
    const float* __restrict__ w_pairv, float* __restrict__ feat)
{
    const int i = blockIdx.x;
    const int t = threadIdx.x;
    __shared__ float tsh[1536];
    __shared__ float pg[288];
    __shared__ float pl[288];
    __shared__ float Rsh[9], Tsh[3];

    for (int idx = t; idx < 1536; idx += 384) tsh[idx] = tmp[(size_t)i * 1536 + idx];
    if (t < 288) pg[t] = outpg[i * 288 + t];
    if (t < 9) Rsh[t] = pose_r[i * 9 + t];
    if (t < 3) Tsh[t] = pose_t[i * 3 + t];
    __syncthreads();

    {
        int h = t >> 5;
        const float* ts = tsh + h * 128;
        float acc = 0.f;
        #pragma unroll 4
        for (int p = 0; p < 128; ++p) acc += ts[p] * w_pairv[p * D_ + t];
        feat[(size_t)i * 1152 + 672 + t] = acc;
    }
    if (t < 288) {
        int x3 = t % 3, base = t - x3;
        float g0 = pg[base + 0] - Tsh[0];
        float g1 = pg[base + 1] - Tsh[1];
        float g2 = pg[base + 2] - Tsh[2];
        float v = Rsh[x3*3+0]*g0 + Rsh[x3*3+1]*g1 + Rsh[x3*3+2]*g2;
        pl[t] = v;
        feat[(size_t)i * 1152 + 384 + t] = v;
    }
    __syncthreads();
    if (t < 96) {
        float a = pl[t*3], b = pl[t*3+1], c = pl[t*3+2];
        feat[(size_t)i * 1152 + 1056 + t] = sqrtf(a*a + b*b + c*c);
    }
}

__global__ __launch_bounds__(384) void k_out_part(
    const float* __restrict__ feat, const float* __restrict__ w_out,
    float* __restrict__ part)
{
    const int kc = blockIdx.x >> 6;
    const int i0 = (blockIdx.x & 63) * 8;
    const int t  = threadIdx.x;
    const int k0 = kc * 144;

    float acc[8];
    #pragma unroll
    for (int r = 0; r < 8; ++r) acc[r] = 0.f;

    for (int d = 0; d < 144; d += 4) {
        float4 fr[8];
        #pragma unroll
        for (int r = 0; r < 8; ++r)
            fr[r] = *(const float4*)(feat + (size_t)(i0 + r) * 1152 + k0 + d);
        #pragma unroll
        for (int e = 0; e < 4; ++e) {
            float wv = w_out[(size_t)(k0 + d + e) * D_ + t];
            #pragma unroll
            for (int r = 0; r < 8; ++r)
                acc[r] += ((const float*)&fr[r])[e] * wv;
        }
    }
    #pragma unroll
    for (int r = 0; r < 8; ++r)
        part[((size_t)kc * N_ + i0 + r) * D_ + t] = acc[r];
}

__global__ __launch_bounds__(256) void k_out_red(
    const float* __restrict__ part, const float* __restrict__ b_out,
    float* __restrict__ out)
{
    const int idx = blockIdx.x * 256 + threadIdx.x;
    float s = b_out[idx % D_];
    #pragma unroll
    for (int kc = 0; kc < 8; ++kc) s += part[(size_t)kc * (N_ * D_) + idx];
    out[idx] = s;
}

extern "C" void kernel_launch(void* const* d_in, const int* in_sizes, int n_in,
                              void* d_out, int out_size, void* d_ws, size_t ws_size,
                              hipStream_t stream)
{
    (void)in_sizes; (void)n_in; (void)out_size; (void)ws_size;
    const float* x1d     = (const float*)d_in[0];
    const float* x2d     = (const float*)d_in[1];
    const float* pose_t  = (const float*)d_in[2];
    const float* pose_r  = (const float*)d_in[3];
    const float* bias    = (const float*)d_in[4];
    const float* w_sq    = (const float*)d_in[5];
    const float* w_sk    = (const float*)d_in[6];
    const float* w_sv    = (const float*)d_in[7];
    const float* w_pb    = (const float*)d_in[8];
    const float* w_pq    = (const float*)d_in[9];
    const float* w_pk    = (const float*)d_in[10];
    const float* w_pv    = (const float*)d_in[11];
    const float* tpw     = (const float*)d_in[12];
    const float* w_pairv = (const float*)d_in[13];
    const float* w_out   = (const float*)d_in[14];
    const float* b_out   = (const float*)d_in[15];
    float* out = (float*)d_out;

    float* ws = (float*)d_ws;
    float* qs      = ws;
    float* kst     = qs      + 196608;
    float* qp      = kst     + 196608;
    float* kpt     = qp      + 73728;
    float* pairlog = kpt     + 73728;    // 3145728 (only 12*512*512 used)
    float* tmp     = pairlog + 3145728;
    float* outpg   = tmp     + 786432;
    float* feat    = outpg   + 147456;
    float* part    = feat    + 589824;   // 1572864 floats
    unsigned short* attn_bf = (unsigned short*)(part + 1572864);  // 12*512*512
    unsigned short* vcatT   = attn_bf + (size_t)12 * N_ * N_;     // 12*64*512

    hipLaunchKernelGGL(k_front, dim3(PROJ_B + PAIR_B), dim3(384), 0, stream,
                       x2d, w_pb, pairlog,
                       x1d, pose_t, pose_r, w_sq, w_sk, w_sv, w_pq, w_pk, w_pv,
                       qs, kst, qp, kpt, vcatT);
    hipLaunchKernelGGL(k_sp_soft, dim3(12 * 128), dim3(256), 0, stream,
                       qs, kst, qp, kpt, bias, tpw, pairlog, attn_bf);
    hipLaunchKernelGGL(k_mid, dim3(512 + 384), dim3(256), 0, stream,
                       attn_bf, x2d, vcatT, tmp, feat, outpg);
    hipLaunchKernelGGL(k_feat, dim3(N_), dim3(384), 0, stream,
                       tmp, outpg, pose_t, pose_r, w_pairv, feat);
    hipLaunchKernelGGL(k_out_part, dim3(512), dim3(384), 0, stream,
                       feat, w_out, part);
    hipLaunchKernelGGL(k_out_red, dim3(768), dim3(256), 0, stream,
                       part, b_out, out);
}

// Round 4
// 350.567 us; speedup vs baseline: 1.1627x; 1.1627x over previous
//
#include <hip/hip_runtime.h>
#include <hip/hip_bf16.h>
#include <math.h>

#define N_  512
#define D_  384
#define H_  12
#define DK_ 32
#define P_  128

#define PROJ_B 320    // proj blocks FIRST (overlap under pair phase)
#define PAIR_B 512    // persistent pair-GEMM blocks, 6 waves each

typedef short short8 __attribute__((ext_vector_type(8)));
typedef float f32x4  __attribute__((ext_vector_type(4)));

typedef const __attribute__((address_space(1))) void GAS;
typedef __attribute__((address_space(3))) void LAS;

static __device__ __forceinline__ unsigned short f2bf(float f) {
    union { float f; unsigned int u; } v; v.f = f;
    unsigned int r = (v.u + 0x7FFFu + ((v.u >> 16) & 1u)) >> 16;  // RNE
    return (unsigned short)r;
}
static __device__ __forceinline__ float bf2f(unsigned short u) {
    union { unsigned int u; float f; } v; v.u = ((unsigned int)u) << 16;
    return v.f;
}
static __device__ __forceinline__ short2 pk2bf(float a, float b) {
    __hip_bfloat162 h = __float22bfloat162_rn(make_float2(a, b));
    return *(short2*)&h;
}
typedef union { short8 v; short2 h2[4]; } s8u;

// ---------------------------------------------------------------------------
// K1: blocks 0..319 = projections+affine (8 rows/block, scheduled first);
// blocks 320..831 = persistent pair-bias MFMA GEMM.
// Pair tiles are DMA'd global->LDS via global_load_lds (width 16, no VGPR
// staging, no scratch). LDS layout is XOR-swizzled by pre-swizzling the
// per-lane GLOBAL source address (gll writes linearly); fragment ds_reads
// use the same involution -> bank-balanced. Per-wave private buffer, no
// barriers; next tile's DMA issued under current tile's convert+MFMA.
// ---------------------------------------------------------------------------
__global__ __launch_bounds__(384) void k_front(
    const float* __restrict__ x2d, const float* __restrict__ w_pb,
    float* __restrict__ pairlog,
    const float* __restrict__ x1d, const float* __restrict__ pose_t,
    const float* __restrict__ pose_r,
    const float* __restrict__ w_sq, const float* __restrict__ w_sk,
    const float* __restrict__ w_sv, const float* __restrict__ w_pq,
    const float* __restrict__ w_pk, const float* __restrict__ w_pv,
    float* __restrict__ qs, float* __restrict__ kst,
    float* __restrict__ qp, float* __restrict__ kpt,
    unsigned short* __restrict__ vcatT)
{
    __shared__ float smem[12288];   // 48KB: pair = 8KB/wave x 6; proj aliases

    const int t = threadIdx.x;

    if (blockIdx.x >= PROJ_B) {
        // ---------------- pair-bias logits (persistent MFMA) ----------------
        const int pb   = blockIdx.x - PROJ_B;   // 0..511
        const int wid  = t >> 6;                // 0..5
        const int lane = t & 63;
        const int quad = lane >> 4;
        const int col  = lane & 15;
        const int gw   = pb * 6 + wid;          // 0..3071 global wave id
        const float pair_w = 0.57735027f;

        float* wl = smem + wid * 2048;          // private 8KB tile buffer

        short8 bfr[4];
        #pragma unroll
        for (int kt = 0; kt < 4; ++kt) {
            #pragma unroll
            for (int jj = 0; jj < 8; ++jj) {
                int p = kt * 32 + quad * 8 + jj;
                bfr[kt][jj] = (col < 12) ? (short)f2bf(w_pb[p * 12 + col]) : (short)0;
            }
        }

        // DMA one 8KB tile (16 rows x 128 p fp32) into wl, source-swizzled.
        // LDS[q] ends up holding tile byte q ^ (((q>>9)&7)<<4) (involution).
        auto GLL = [&](int T) {
            const char* tb = (const char*)(x2d
                + ((size_t)((T >> 5) * N_ + ((T & 31) << 4))) * P_);
            #pragma unroll
            for (int k = 0; k < 8; ++k) {
                int q   = k * 1024 + lane * 16;
                int src = q ^ (((q >> 9) & 7) << 4);
                __builtin_amdgcn_global_load_lds(
                    (GAS*)(tb + src),
                    (LAS*)((char*)wl + k * 1024),
                    16, 0, 0);
            }
        };

        const bool has6 = (gw + 15360) < 16384;
        const int  nt   = has6 ? 6 : 5;

        int T = gw;
        GLL(T);
        for (int s = 0; s < nt; ++s) {
            asm volatile("s_waitcnt vmcnt(0)" ::: "memory");   // tile s in LDS

            // fragment reads (swizzled): row=col, floats kt*32+quad*8 .. +8
            float4 xf[8];
            #pragma unroll
            for (int kt = 0; kt < 4; ++kt) {
                int g0 = (col * 512 + kt * 128 + quad * 32) ^ ((col & 7) << 4);
                xf[2*kt]   = *(const float4*)((const char*)wl + g0);
                xf[2*kt+1] = *(const float4*)((const char*)wl + (g0 ^ 16));
            }
            asm volatile("s_waitcnt lgkmcnt(0)" ::: "memory"); // frags in regs

            const int Tn = T + 3072;
            if (s + 1 < nt) GLL(Tn);   // overwrite OK, overlaps compute below

            f32x4 acc = {0.f, 0.f, 0.f, 0.f};
            #pragma unroll
            for (int kt = 0; kt < 4; ++kt) {
                s8u afr;
                afr.h2[0] = pk2bf(xf[2*kt].x,   xf[2*kt].y);
                afr.h2[1] = pk2bf(xf[2*kt].z,   xf[2*kt].w);
                afr.h2[2] = pk2bf(xf[2*kt+1].x, xf[2*kt+1].y);
                afr.h2[3] = pk2bf(xf[2*kt+1].z, xf[2*kt+1].w);
                acc = __builtin_amdgcn_mfma_f32_16x16x32_bf16(afr.v, bfr[kt], acc, 0, 0, 0);
            }
            if (col < 12) {
                const int i  = T >> 5;
                const int j0 = (T & 31) << 4;
                float4 st = make_float4(pair_w * acc[0], pair_w * acc[1],
                                        pair_w * acc[2], pair_w * acc[3]);
                *(float4*)(pairlog + ((size_t)(col * N_ + i)) * N_ + j0 + quad * 4) = st;
            }
            T = Tn;
        }
        return;
    }

    // ---------------- projections + affine (8 rows/block) ----------------
    float (*raw)[288] = reinterpret_cast<float(*)[288]>(smem);
    float (*Rsh)[9]   = reinterpret_cast<float(*)[9]>(smem + 2304);
    float (*Tsh)[3]   = reinterpret_cast<float(*)[3]>(smem + 2304 + 72);

    const int b   = blockIdx.x;
    const int seg = b >> 6;            // 0..4
    const int i0  = (b & 63) * 8;

    if (seg < 3) {
        const float* __restrict__ w = (seg == 0) ? w_sq : (seg == 1) ? w_sk : w_sv;
        float acc[8];
        #pragma unroll
        for (int r = 0; r < 8; ++r) acc[r] = 0.f;
        for (int d = 0; d < D_; d += 4) {
            float4 xr[8];
            #pragma unroll
            for (int r = 0; r < 8; ++r)
                xr[r] = *(const float4*)(x1d + (i0 + r) * D_ + d);
            #pragma unroll
            for (int e = 0; e < 4; ++e) {
                float wv = w[(d + e) * D_ + t];
                #pragma unroll
                for (int r = 0; r < 8; ++r)
                    acc[r] += ((const float*)&xr[r])[e] * wv;
            }
        }
        if (seg == 0) {
            #pragma unroll
            for (int r = 0; r < 8; ++r) qs[(i0 + r) * D_ + t] = acc[r];
        } else if (seg == 1) {
            *(float4*)(kst + t * N_ + i0)     = make_float4(acc[0], acc[1], acc[2], acc[3]);
            *(float4*)(kst + t * N_ + i0 + 4) = make_float4(acc[4], acc[5], acc[6], acc[7]);
        } else {
            int h = t >> 5, c = t & 31;
            s8u sv;
            #pragma unroll
            for (int r = 0; r < 4; ++r) sv.h2[r] = pk2bf(acc[2*r], acc[2*r+1]);
            *(short8*)(vcatT + ((size_t)h * 64 + c) * N_ + i0) = sv.v;
        }
    } else {
        if (t < 72) Rsh[t / 9][t % 9] = pose_r[(i0 + t / 9) * 9 + t % 9];
        else if (t < 96) {
            int r = (t - 72) / 3, c = (t - 72) % 3;
            Tsh[r][c] = pose_t[(i0 + r) * 3 + c];
        }

        if (t < 288) {
            const float* __restrict__ w;
            int col, ldw;
            if (seg == 3) {
                if (t < 144) { w = w_pq; col = t;       ldw = 144; }
                else         { w = w_pk; col = t - 144; ldw = 144; }
            } else         { w = w_pv; col = t;       ldw = 288; }
            float acc[8];
            #pragma unroll
            for (int r = 0; r < 8; ++r) acc[r] = 0.f;
            for (int d = 0; d < D_; d += 4) {
                float4 xr[8];
                #pragma unroll
                for (int r = 0; r < 8; ++r)
                    xr[r] = *(const float4*)(x1d + (i0 + r) * D_ + d);
                #pragma unroll
                for (int e = 0; e < 4; ++e) {
                    float wv = w[(d + e) * ldw + col];
                    #pragma unroll
                    for (int r = 0; r < 8; ++r)
                        acc[r] += ((const float*)&xr[r])[e] * wv;
                }
            }
            #pragma unroll
            for (int r = 0; r < 8; ++r) raw[r][t] = acc[r];
        }
        __syncthreads();

        if (t < 288) {
            const int x3   = t % 3;
            const int base = t - x3;
            if (seg == 3) {
                const int c = (t < 144) ? t : t - 144;
                if (t < 144) {
                    #pragma unroll
                    for (int r = 0; r < 8; ++r) {
                        float g = Rsh[r][0 + x3] * raw[r][base]
                                + Rsh[r][3 + x3] * raw[r][base + 1]
                                + Rsh[r][6 + x3] * raw[r][base + 2] + Tsh[r][x3];
                        qp[(i0 + r) * 144 + c] = g;
                    }
                } else {
                    float g[8];
                    #pragma unroll
                    for (int r = 0; r < 8; ++r)
                        g[r] = Rsh[r][0 + x3] * raw[r][base]
                             + Rsh[r][3 + x3] * raw[r][base + 1]
                             + Rsh[r][6 + x3] * raw[r][base + 2] + Tsh[r][x3];
                    *(float4*)(kpt + c * N_ + i0)     = make_float4(g[0], g[1], g[2], g[3]);
                    *(float4*)(kpt + c * N_ + i0 + 4) = make_float4(g[4], g[5], g[6], g[7]);
                }
            } else {
                int h = t / 24, pc = t % 24;
                float g[8];
                #pragma unroll
                for (int r = 0; r < 8; ++r)
                    g[r] = Rsh[r][0 + x3] * raw[r][base]
                         + Rsh[r][3 + x3] * raw[r][base + 1]
                         + Rsh[r][6 + x3] * raw[r][base + 2] + Tsh[r][x3];
                s8u sv;
                #pragma unroll
                for (int r = 0; r < 4; ++r) sv.h2[r] = pk2bf(g[2*r], g[2*r+1]);
                *(short8*)(vcatT + ((size_t)h * 64 + 32 + pc) * N_ + i0) = sv.v;
            }
        }
    }
}

// ---------------------------------------------------------------------------
// K2 (fused): scalar+point+bias logits + pair logits read + softmax,
// all in registers. Writes ONLY bf16 attn. Block = (h, 4 rows), 256 thr.
// ---------------------------------------------------------------------------
__global__ __launch_bounds__(256) void k_sp_soft(
    const float* __restrict__ qs, const float* __restrict__ kst,
    const float* __restrict__ qp, const float* __restrict__ kpt,
    const float* __restrict__ bias, const float* __restrict__ tpw,
    const float* __restrict__ pairlog,
    unsigned short* __restrict__ attn_bf)
{
    const int h  = blockIdx.x / 128;
    const int i0 = (blockIdx.x % 128) * 4;
    const int t  = threadIdx.x;
    const int lane = t & 63;
    const int wid  = t >> 6;
    __shared__ float qsh[4][32];
    __shared__ float qph[4][12];
    __shared__ float wredm[4][4];
    __shared__ float wreds[4][4];
    if (t < 128) { int il = t / 32, c = t % 32; qsh[il][c] = qs[(i0+il) * D_ + h*32 + c]; }
    else if (t < 176) { int r = t - 128; int il = r / 12, c = r % 12; qph[il][c] = qp[(i0+il)*144 + h*12 + c]; }
    const float pwh = 0.13608276f * log1pf(expf(tpw[h]));
    const float scalar_w = 0.10206207f;
    __syncthreads();

    float v[4][2];
    for (int jh = 0; jh < 2; ++jh) {
        int j = t + jh * 256;
        float kv[32];
        #pragma unroll
        for (int c = 0; c < 32; ++c) kv[c] = kst[(h*32 + c) * N_ + j];
        float kp[12];
        #pragma unroll
        for (int c = 0; c < 12; ++c) kp[c] = kpt[(h*12 + c) * N_ + j];

        #pragma unroll
        for (int il = 0; il < 4; ++il) {
            float s = 0.f;
            #pragma unroll
            for (int c = 0; c < 32; ++c) s += qsh[il][c] * kv[c];
            float dsum = 0.f;
            #pragma unroll
            for (int p = 0; p < 4; ++p) {
                float dx = qph[il][p*3+0] - kp[p*3+0];
                float dy = qph[il][p*3+1] - kp[p*3+1];
                float dz = qph[il][p*3+2] - kp[p*3+2];
                dsum += sqrtf(dx*dx + dy*dy + dz*dz);
            }
            v[il][jh] = scalar_w * s - 0.5f * pwh * dsum
                      + bias[(i0+il) * N_ + j]
                      + pairlog[((size_t)(h * N_ + (i0+il))) * N_ + j];
        }
    }

    // row max
    #pragma unroll
    for (int il = 0; il < 4; ++il) {
        float mt = fmaxf(v[il][0], v[il][1]);
        #pragma unroll
        for (int off = 1; off < 64; off <<= 1)
            mt = fmaxf(mt, __shfl_xor(mt, off));
        if (lane == 0) wredm[il][wid] = mt;
    }
    __syncthreads();
    float m[4];
    #pragma unroll
    for (int il = 0; il < 4; ++il)
        m[il] = fmaxf(fmaxf(wredm[il][0], wredm[il][1]),
                      fmaxf(wredm[il][2], wredm[il][3]));

    // exp + row sum
    #pragma unroll
    for (int il = 0; il < 4; ++il) {
        float e0 = __expf(v[il][0] - m[il]);
        float e1 = __expf(v[il][1] - m[il]);
        v[il][0] = e0; v[il][1] = e1;
        float st = e0 + e1;
        #pragma unroll
        for (int off = 1; off < 64; off <<= 1)
            st += __shfl_xor(st, off);
        if (lane == 0) wreds[il][wid] = st;
    }
    __syncthreads();
    #pragma unroll
    for (int il = 0; il < 4; ++il) {
        float inv = 1.0f / (wreds[il][0] + wreds[il][1] + wreds[il][2] + wreds[il][3]);
        size_t base = ((size_t)(h * N_ + i0 + il)) * N_;
        attn_bf[base + t]       = f2bf(v[il][0] * inv);
        attn_bf[base + t + 256] = f2bf(v[il][1] * inv);
    }
}

// ---------------------------------------------------------------------------
// K3 (merged): blocks 0..511 = tmp (attn_bf @ x2d per row i);
// blocks 512..895 = aggr (attn_bf @ vcatT via MFMA).
// ---------------------------------------------------------------------------
__global__ __launch_bounds__(256) void k_mid(
    const unsigned short* __restrict__ attn_bf,
    const float* __restrict__ x2d,
    const unsigned short* __restrict__ vcatT,
    float* __restrict__ tmp,
    float* __restrict__ feat, float* __restrict__ outpg)
{
    __shared__ float4 at[3][N_];
    __shared__ float red[4][1536];

    const int t = threadIdx.x;

    if (blockIdx.x < 512) {
        const int i = blockIdx.x;
        // stage bf16 attn -> fp32 LDS
        for (int idx = t; idx < 12 * N_; idx += 256) {
            int h = idx >> 9, j = idx & 511;
            float a = bf2f(attn_bf[((size_t)(h * N_ + i)) * N_ + j]);
            ((float*)&at[h >> 2][j])[h & 3] = a;
        }
        __syncthreads();

        const int p2 = (t & 63) * 2;
        const int jh = t >> 6;
        float acc[12][2];
        #pragma unroll
        for (int h = 0; h < 12; ++h) { acc[h][0] = 0.f; acc[h][1] = 0.f; }
        const float* xb = x2d + (size_t)i * N_ * P_;

        #pragma unroll 4
        for (int j = jh; j < N_; j += 4) {
            float2 x = *(const float2*)(xb + j * P_ + p2);
            float4 a0 = at[0][j], a1 = at[1][j], a2 = at[2][j];
            acc[0][0]  += a0.x*x.x; acc[0][1]  += a0.x*x.y;
            acc[1][0]  += a0.y*x.x; acc[1][1]  += a0.y*x.y;
            acc[2][0]  += a0.z*x.x; acc[2][1]  += a0.z*x.y;
            acc[3][0]  += a0.w*x.x; acc[3][1]  += a0.w*x.y;
            acc[4][0]  += a1.x*x.x; acc[4][1]  += a1.x*x.y;
            acc[5][0]  += a1.y*x.x; acc[5][1]  += a1.y*x.y;
            acc[6][0]  += a1.z*x.x; acc[6][1]  += a1.z*x.y;
            acc[7][0]  += a1.w*x.x; acc[7][1]  += a1.w*x.y;
            acc[8][0]  += a2.x*x.x; acc[8][1]  += a2.x*x.y;
            acc[9][0]  += a2.y*x.x; acc[9][1]  += a2.y*x.y;
            acc[10][0] += a2.z*x.x; acc[10][1] += a2.z*x.y;
            acc[11][0] += a2.w*x.x; acc[11][1] += a2.w*x.y;
        }
        #pragma unroll
        for (int h = 0; h < 12; ++h) {
            red[jh][h * 128 + p2]     = acc[h][0];
            red[jh][h * 128 + p2 + 1] = acc[h][1];
        }
        __syncthreads();
        for (int idx = t; idx < 1536; idx += 256)
            tmp[(size_t)i * 1536 + idx] = red[0][idx] + red[1][idx] + red[2][idx] + red[3][idx];
        return;
    }

    // ---------------- aggr (MFMA) ----------------
    const int bid  = blockIdx.x - 512;
    const int h    = bid >> 5;
    const int i0   = (bid & 31) << 4;
    const int wid  = t >> 6;
    const int lane = t & 63;
    const int quad = lane >> 4;
    const int col  = lane & 15;
    const int c    = wid * 16 + col;
    const bool cvalid = (c < 56);

    const unsigned short* arow = attn_bf + ((size_t)(h * N_ + i0 + col)) * N_;
    const unsigned short* brow = vcatT + ((size_t)h * 64 + c) * N_;

    f32x4 acc = {0.f, 0.f, 0.f, 0.f};
    #pragma unroll
    for (int kt = 0; kt < 16; ++kt) {
        const int k0 = kt * 32 + quad * 8;
        short8 a = *(const short8*)(arow + k0);
        short8 b;
        if (cvalid) b = *(const short8*)(brow + k0);
        else { b[0]=0;b[1]=0;b[2]=0;b[3]=0;b[4]=0;b[5]=0;b[6]=0;b[7]=0; }
        acc = __builtin_amdgcn_mfma_f32_16x16x32_bf16(a, b, acc, 0, 0, 0);
    }
    #pragma unroll
    for (int r = 0; r < 4; ++r) {
        int i = i0 + quad * 4 + r;
        if (c < 32)       feat[(size_t)i * 1152 + h * 32 + c] = acc[r];
        else if (c < 56)  outpg[((size_t)i * 12 + h) * 24 + (c - 32)] = acc[r];
    }
}

__global__ __launch_bounds__(384) void k_feat(
    const float* __restrict__ tmp, const float* __restrict__ outpg,
    const float* __restrict__ pose_t, const float* __restrict__ pose_r,
    const float* __restrict__ w_pairv, float* __restrict__ feat)
{
    const int i = blockIdx.x;
    const int t = threadIdx.x;
    __shared__ float tsh[1536];
    __shared__ float pg[288];
    __shared__ float pl[288];
    __shared__ float Rsh[9], Tsh[3];

    for (int idx = t; idx < 1536; idx += 384) tsh[idx] = tmp[(size_t)i * 1536 + idx];
    if (t < 288) pg[t] = outpg[i * 288 + t];
    if (t < 9) Rsh[t] = pose_r[i * 9 + t];
    if (t < 3) Tsh[t] = pose_t[i * 3 + t];
    __syncthreads();

    {
        int h = t >> 5;
        const float* ts = tsh + h * 128;
        float acc = 0.f;
        #pragma unroll 4
        for (int p = 0; p < 128; ++p) acc += ts[p] * w_pairv[p * D_ + t];
        feat[(size_t)i * 1152 + 672 + t] = acc;
    }
    if (t < 288) {
        int x3 = t % 3, base = t - x3;
        float g0 = pg[base + 0] - Tsh[0];
        float g1 = pg[base + 1] - Tsh[1];
        float g2 = pg[base + 2] - Tsh[2];
        float v = Rsh[x3*3+0]*g0 + Rsh[x3*3+1]*g1 + Rsh[x3*3+2]*g2;
        pl[t] = v;
        feat[(size_t)i * 1152 + 384 + t] = v;
    }
    __syncthreads();
    if (t < 96) {
        float a = pl[t*3], b = pl[t*3+1], c = pl[t*3+2];
        feat[(size_t)i * 1152 + 1056 + t] = sqrtf(a*a + b*b + c*c);
    }
}

__global__ __launch_bounds__(384) void k_out_part(
    const float* __restrict__ feat, const float* __restrict__ w_out,
    float* __restrict__ part)
{
    const int kc = blockIdx.x >> 6;
    const int i0 = (blockIdx.x & 63) * 8;
    const int t  = threadIdx.x;
    const int k0 = kc * 144;

    float acc[8];
    #pragma unroll
    for (int r = 0; r < 8; ++r) acc[r] = 0.f;

    for (int d = 0; d < 144; d += 4) {
        float4 fr[8];
        #pragma unroll
        for (int r = 0; r < 8; ++r)
            fr[r] = *(const float4*)(feat + (size_t)(i0 + r) * 1152 + k0 + d);
        #pragma unroll
        for (int e = 0; e < 4; ++e) {
            float wv = w_out[(size_t)(k0 + d + e) * D_ + t];
            #pragma unroll
            for (int r = 0; r < 8; ++r)
                acc[r] += ((const float*)&fr[r])[e] * wv;
        }
    }
    #pragma unroll
    for (int r = 0; r < 8; ++r)
        part[((size_t)kc * N_ + i0 + r) * D_ + t] = acc[r];
}

__global__ __launch_bounds__(256) void k_out_red(
    const float* __restrict__ part, const float* __restrict__ b_out,
    float* __restrict__ out)
{
    const int idx = blockIdx.x * 256 + threadIdx.x;
    float s = b_out[idx % D_];
    #pragma unroll
    for (int kc = 0; kc < 8; ++kc) s += part[(size_t)kc * (N_ * D_) + idx];
    out[idx] = s;
}

extern "C" void kernel_launch(void* const* d_in, const int* in_sizes, int n_in,
                              void* d_out, int out_size, void* d_ws, size_t ws_size,
                              hipStream_t stream)
{
    (void)in_sizes; (void)n_in; (void)out_size; (void)ws_size;
    const float* x1d     = (const float*)d_in[0];
    const float* x2d     = (const float*)d_in[1];
    const float* pose_t  = (const float*)d_in[2];
    const float* pose_r  = (const float*)d_in[3];
    const float* bias    = (const float*)d_in[4];
    const float* w_sq    = (const float*)d_in[5];
    const float* w_sk    = (const float*)d_in[6];
    const float* w_sv    = (const float*)d_in[7];
    const float* w_pb    = (const float*)d_in[8];
    const float* w_pq    = (const float*)d_in[9];
    const float* w_pk    = (const float*)d_in[10];
    const float* w_pv    = (const float*)d_in[11];
    const float* tpw     = (const float*)d_in[12];
    const float* w_pairv = (const float*)d_in[13];
    const float* w_out   = (const float*)d_in[14];
    const float* b_out   = (const float*)d_in[15];
    float* out = (float*)d_out;

    float* ws = (float*)d_ws;
    float* qs      = ws;
    float* kst     = qs      + 196608;
    float* qp      = kst     + 196608;
    float* kpt     = qp      + 73728;
    float* pairlog = kpt     + 73728;    // 3145728 (only 12*512*512 used)
    float* tmp     = pairlog + 3145728;
    float* outpg   = tmp     + 786432;
    float* feat    = outpg   + 147456;
    float* part    = feat    + 589824;   // 1572864 floats
    unsigned short* attn_bf = (unsigned short*)(part + 1572864);  // 12*512*512
    unsigned short* vcatT   = attn_bf + (size_t)12 * N_ * N_;     // 12*64*512

    hipLaunchKernelGGL(k_front, dim3(PROJ_B + PAIR_B), dim3(384), 0, stream,
                       x2d, w_pb, pairlog,
                       x1d, pose_t, pose_r, w_sq, w_sk, w_sv, w_pq, w_pk, w_pv,
                       qs, kst, qp, kpt, vcatT);
    hipLaunchKernelGGL(k_sp_soft, dim3(12 * 128), dim3(256), 0, stream,
                       qs, kst, qp, kpt, bias, tpw, pairlog, attn_bf);
    hipLaunchKernelGGL(k_mid, dim3(512 + 384), dim3(256), 0, stream,
                       attn_bf, x2d, vcatT, tmp, feat, outpg);
    hipLaunchKernelGGL(k_feat, dim3(N_), dim3(384), 0, stream,
                       tmp, outpg, pose_t, pose_r, w_pairv, feat);
    hipLaunchKernelGGL(k_out_part, dim3(512), dim3(384), 0, stream,
                       feat, w_out, part);
    hipLaunchKernelGGL(k_out_red, dim3(768), dim3(256), 0, stream,
                       part, b_out, out);
}